// Round 1
// baseline (73.956 us; speedup 1.0000x reference)
//
#include <hip/hip_runtime.h>
#include <math.h>

#define B   8
#define C   1024
#define M   8
#define HW  4096
#define EPS 1e-6f
#define GAIN 0.3f

#define NT  8            // hw tiles per batch
#define NC  8            // channel chunks
#define HWT (HW/NT)      // 512 hw per tile
#define CCH (C/NC)       // 128 channels per chunk
#define TPB 256          // threads per block (each thread: 2 hw via float2)

// workspace layout (float offsets)
#define OFF_YZP   0                          // [B][NC][M][HW]  = 2097152
#define OFF_STATP (OFF_YZP + B*NC*M*HW)      // [B][NT*NC][2]   = 1024
#define OFF_STATS (OFF_STATP + B*NT*NC*2)    // [B][2] (mu,istd)= 16
#define OFF_S     (OFF_STATS + B*2)          // [M]             = 8
#define OFF_Y     (OFF_S + M)                // [B][M][HW]      = 262144
#define WS_FLOATS (OFF_Y + B*M*HW)

// ---------------- K1: partial stats + partial yz = W @ z (per c-chunk) -----
__global__ __launch_bounds__(TPB) void k1_partial(const float* __restrict__ z,
                                                  const float* __restrict__ Wd,
                                                  float* __restrict__ ws) {
    int bid = blockIdx.x;
    int nc  = bid % NC;
    int t   = (bid / NC) % NT;
    int b   = bid / (NC * NT);
    int tid = threadIdx.x;
    int hw  = t * HWT + tid * 2;
    int c0  = nc * CCH;

    float2 ym[M];
#pragma unroll
    for (int m = 0; m < M; ++m) ym[m] = make_float2(0.f, 0.f);
    float su = 0.f, sq = 0.f;

    const float* zp = z + ((size_t)(b * C + c0)) * HW + hw;
#pragma unroll 4
    for (int ci = 0; ci < CCH; ++ci) {
        float2 v = *reinterpret_cast<const float2*>(zp + (size_t)ci * HW);
        su += v.x + v.y;
        sq += v.x * v.x + v.y * v.y;
        int c = c0 + ci;
#pragma unroll
        for (int m = 0; m < M; ++m) {
            float w = Wd[m * C + c];           // uniform -> s_load
            ym[m].x += w * v.x;
            ym[m].y += w * v.y;
        }
    }

    // write yz partials: [b][nc][m][hw]
    float* yzp = ws + OFF_YZP + ((size_t)(b * NC + nc) * M) * HW + hw;
#pragma unroll
    for (int m = 0; m < M; ++m)
        *reinterpret_cast<float2*>(yzp + (size_t)m * HW) = ym[m];

    // deterministic block tree-reduce of stats
    __shared__ float red[2 * TPB];
    red[tid] = su;
    red[TPB + tid] = sq;
    __syncthreads();
    for (int s = TPB / 2; s > 0; s >>= 1) {
        if (tid < s) {
            red[tid] += red[tid + s];
            red[TPB + tid] += red[TPB + tid + s];
        }
        __syncthreads();
    }
    if (tid == 0) {
        float* st = ws + OFF_STATP + ((size_t)b * (NT * NC) + t * NC + nc) * 2;
        st[0] = red[0];
        st[1] = red[TPB];
    }
}

// ---------------- K2: finalize mu/istd per batch + s[m] = sum_c W[m,c] -----
__global__ __launch_bounds__(512) void k2_finalize(const float* __restrict__ Wd,
                                                   float* __restrict__ ws) {
    int tid = threadIdx.x;      // 512 threads = 8 waves
    int w   = tid >> 6;         // wave id 0..7
    int l   = tid & 63;

    // stats for batch b = w  (64 partials, one per lane)
    {
        const float* sp = ws + OFF_STATP + ((size_t)w * (NT * NC) + l) * 2;
        float su = sp[0], sq = sp[1];
#pragma unroll
        for (int o = 32; o > 0; o >>= 1) {
            su += __shfl_down(su, o);
            sq += __shfl_down(sq, o);
        }
        if (l == 0) {
            const float invN = 1.0f / (float)(C * HW);
            float mu  = su * invN;
            float var = sq * invN - mu * mu;
            float istd = 1.0f / sqrtf(var + EPS);
            ws[OFF_STATS + w * 2]     = mu;
            ws[OFF_STATS + w * 2 + 1] = istd;
        }
    }
    // s[m] for m = w
    {
        float sm = 0.f;
#pragma unroll
        for (int k = 0; k < C / 64; ++k) sm += Wd[w * C + k * 64 + l];
#pragma unroll
        for (int o = 32; o > 0; o >>= 1) sm += __shfl_down(sm, o);
        if (l == 0) ws[OFF_S + w] = sm;
    }
}

// ---------------- K3: reduce yz chunk-partials, apply norm -> y ------------
__global__ __launch_bounds__(TPB) void k3_reduce_y(float* __restrict__ ws) {
    int gid = blockIdx.x * TPB + threadIdx.x;   // 512*256 threads, 2 elems each
    int hw2 = gid % (HW / 2);
    int rem = gid / (HW / 2);
    int m   = rem % M;
    int b   = rem / M;
    int hw  = hw2 * 2;

    float2 acc = make_float2(0.f, 0.f);
    const float* p = ws + OFF_YZP + ((size_t)b * NC * M + m) * HW + hw;
#pragma unroll
    for (int nc = 0; nc < NC; ++nc) {
        float2 v = *reinterpret_cast<const float2*>(p + (size_t)nc * M * HW);
        acc.x += v.x;
        acc.y += v.y;
    }
    float mu   = ws[OFF_STATS + b * 2];
    float istd = ws[OFF_STATS + b * 2 + 1];
    float sm   = ws[OFF_S + m];
    float2 y;
    y.x = istd * (acc.x - mu * sm);
    y.y = istd * (acc.y - mu * sm);
    *reinterpret_cast<float2*>(ws + OFF_Y + ((size_t)b * M + m) * HW + hw) = y;
}

// ---------------- K4: out = z + GAIN * W^T y -------------------------------
__global__ __launch_bounds__(TPB) void k4_apply(const float* __restrict__ z,
                                                const float* __restrict__ Wd,
                                                const float* __restrict__ ws,
                                                float* __restrict__ out) {
    int bid = blockIdx.x;
    int nc  = bid % NC;
    int t   = (bid / NC) % NT;
    int b   = bid / (NC * NT);
    int tid = threadIdx.x;
    int hw  = t * HWT + tid * 2;
    int c0  = nc * CCH;

    // y[m] for this thread's two hw positions: 16 VGPRs
    float2 y[M];
    const float* yp = ws + OFF_Y + (size_t)b * M * HW + hw;
#pragma unroll
    for (int m = 0; m < M; ++m)
        y[m] = *reinterpret_cast<const float2*>(yp + (size_t)m * HW);

    const float* zp = z + ((size_t)(b * C + c0)) * HW + hw;
    float* op = out + ((size_t)(b * C + c0)) * HW + hw;
#pragma unroll 4
    for (int ci = 0; ci < CCH; ++ci) {
        float2 v = *reinterpret_cast<const float2*>(zp + (size_t)ci * HW);
        int c = c0 + ci;
        float rx = 0.f, ry = 0.f;
#pragma unroll
        for (int m = 0; m < M; ++m) {
            float w = Wd[m * C + c];           // uniform -> s_load
            rx += w * y[m].x;
            ry += w * y[m].y;
        }
        float2 o;
        o.x = v.x + GAIN * rx;
        o.y = v.y + GAIN * ry;
        *reinterpret_cast<float2*>(op + (size_t)ci * HW) = o;
    }
}

extern "C" void kernel_launch(void* const* d_in, const int* in_sizes, int n_in,
                              void* d_out, int out_size, void* d_ws, size_t ws_size,
                              hipStream_t stream) {
    const float* z  = (const float*)d_in[0];   // (8,1024,64,64) fp32
    const float* Wd = (const float*)d_in[1];   // (8,1024) fp32
    float* out = (float*)d_out;                // (8,1024,64,64) fp32
    float* ws  = (float*)d_ws;                 // needs WS_FLOATS*4 ≈ 9.45 MB

    dim3 blk(TPB);
    k1_partial<<<dim3(B * NT * NC), blk, 0, stream>>>(z, Wd, ws);
    k2_finalize<<<dim3(1), dim3(512), 0, stream>>>(Wd, ws);
    k3_reduce_y<<<dim3((B * M * HW / 2) / TPB), blk, 0, stream>>>(ws);
    k4_apply<<<dim3(B * NT * NC), blk, 0, stream>>>(z, Wd, ws, out);
}